// Round 1
// baseline (302.976 us; speedup 1.0000x reference)
//
#include <hip/hip_runtime.h>

// NNUE (HalfKA) fused forward pass for MI355X.
// One 256-thread block per sample; thread t owns fp32 columns [4t, 4t+4).

#define FEATS 32
#define FTO   1024
#define HH    512

__device__ __forceinline__ float clip127(float x) {
    return fminf(fmaxf(x, 0.0f), 127.0f);
}

__global__ __launch_bounds__(256) void nnue_fwd(
    const int*   __restrict__ w_feats,
    const int*   __restrict__ b_feats,
    const int*   __restrict__ stm,
    const int*   __restrict__ bucket,
    const float* __restrict__ ft_w,
    const float* __restrict__ ft_bias,
    const float* __restrict__ psqt_w,
    const float* __restrict__ fc0_w,
    const float* __restrict__ fc0_b,
    const float* __restrict__ fc1_w,
    const float* __restrict__ fc1_b,
    const float* __restrict__ fc2_w,
    const float* __restrict__ fc2_b,
    float*       __restrict__ out)
{
    const int b   = blockIdx.x;
    const int tid = threadIdx.x;

    __shared__ int   sfw[FEATS];
    __shared__ int   sfb[FEATS];
    __shared__ float s_acc[2][FTO];   // [0]=acc_stm, [1]=acc_opp
    __shared__ float s_part[4][16];   // fc0 per-wave partials
    __shared__ float s_o0[16];
    __shared__ float s_psqt[16];      // [0..7]=white bag, [8..15]=black bag

    if (tid < FEATS)          sfw[tid]         = w_feats[b * FEATS + tid];
    else if (tid < 2 * FEATS) sfb[tid - FEATS] = b_feats[b * FEATS + (tid - FEATS)];
    __syncthreads();

    // ---- feature-transformer gather-sum (the hot part) ----
    const float4* __restrict__ ftw4 = reinterpret_cast<const float4*>(ft_w);
    const float4 bias4 = reinterpret_cast<const float4*>(ft_bias)[tid];
    float4 aw = bias4, ab = bias4;

    #pragma unroll 8
    for (int k = 0; k < FEATS; ++k) {
        const float4 rw = ftw4[(size_t)sfw[k] * 256 + tid];
        const float4 rb = ftw4[(size_t)sfb[k] * 256 + tid];
        aw.x += rw.x; aw.y += rw.y; aw.z += rw.z; aw.w += rw.w;
        ab.x += rb.x; ab.y += rb.y; ab.z += rb.z; ab.w += rb.w;
    }

    // ---- psqt gather-sum (tiny, L2-resident table) ----
    if (tid < 16) {
        const int* f = (tid < 8) ? sfw : sfb;
        const int  j = tid & 7;
        float s = 0.0f;
        #pragma unroll 4
        for (int k = 0; k < FEATS; ++k) s += psqt_w[(size_t)f[k] * 8 + j];
        s_psqt[tid] = s;
    }

    const int st = stm[b];
    const float4 astm = st ? ab : aw;
    const float4 aopp = st ? aw : ab;

    reinterpret_cast<float4*>(&s_acc[0][0])[tid] = astm;
    reinterpret_cast<float4*>(&s_acc[1][0])[tid] = aopp;
    __syncthreads();

    // ---- pairwise clip-mult: ft[h] = clip(a[h])*clip(a[h+512])/128 ----
    float4 ft4;
    if (tid < 128) {
        const float4 lo = astm;  // own cols < 512
        const float4 hi = *reinterpret_cast<const float4*>(&s_acc[0][HH + tid * 4]);
        ft4.x = clip127(lo.x) * clip127(hi.x) * (1.0f/128.0f);
        ft4.y = clip127(lo.y) * clip127(hi.y) * (1.0f/128.0f);
        ft4.z = clip127(lo.z) * clip127(hi.z) * (1.0f/128.0f);
        ft4.w = clip127(lo.w) * clip127(hi.w) * (1.0f/128.0f);
    } else {
        const float4 lo = *reinterpret_cast<const float4*>(&s_acc[1][(tid - 128) * 4]);
        const float4 hi = aopp;  // own cols >= 512
        ft4.x = clip127(lo.x) * clip127(hi.x) * (1.0f/128.0f);
        ft4.y = clip127(lo.y) * clip127(hi.y) * (1.0f/128.0f);
        ft4.z = clip127(lo.z) * clip127(hi.z) * (1.0f/128.0f);
        ft4.w = clip127(lo.w) * clip127(hi.w) * (1.0f/128.0f);
    }

    // ---- fc0: 16 outputs, dot over 1024 ----
    const int bk = bucket[b];
    const float4* __restrict__ w0 =
        reinterpret_cast<const float4*>(fc0_w + (size_t)bk * 16 * FTO);
    float p[16];
    #pragma unroll
    for (int o = 0; o < 16; ++o) {
        const float4 w = w0[o * 256 + tid];
        p[o] = ft4.x * w.x + ft4.y * w.y + ft4.z * w.z + ft4.w * w.w;
    }
    const int lane = tid & 63;
    const int wv   = tid >> 6;
    #pragma unroll
    for (int o = 0; o < 16; ++o) {
        float v = p[o];
        v += __shfl_down(v, 32);
        v += __shfl_down(v, 16);
        v += __shfl_down(v, 8);
        v += __shfl_down(v, 4);
        v += __shfl_down(v, 2);
        v += __shfl_down(v, 1);
        if (lane == 0) s_part[wv][o] = v;
    }
    __syncthreads();
    if (tid < 16) {
        s_o0[tid] = s_part[0][tid] + s_part[1][tid] + s_part[2][tid] + s_part[3][tid]
                  + fc0_b[bk * 16 + tid];
    }
    __syncthreads();

    // ---- tail: fc1 (32x32), fc2 (1x32), skip, psqt ----
    if (tid < 32) {
        const float* __restrict__ w1 = fc1_w + ((size_t)bk * 32 + tid) * 32;
        float o1 = fc1_b[bk * 32 + tid];
        #pragma unroll
        for (int i = 0; i < 15; ++i) {
            const float o0i = s_o0[i];
            const float sq  = clip127(o0i * o0i * (1.0f/524288.0f));
            const float rl  = clip127(o0i * (1.0f/64.0f));
            o1 += sq * w1[i] + rl * w1[15 + i];
        }
        const float ac1 = clip127(o1 * (1.0f/64.0f));
        float v = ac1 * fc2_w[bk * 32 + tid];
        v += __shfl_down(v, 16);
        v += __shfl_down(v, 8);
        v += __shfl_down(v, 4);
        v += __shfl_down(v, 2);
        v += __shfl_down(v, 1);
        if (tid == 0) {
            const float scalar = v + fc2_b[bk];
            const float skip   = s_o0[15] * (9600.0f / 8128.0f);
            const float p_stm  = st ? s_psqt[8 + bk] : s_psqt[bk];
            const float p_opp  = st ? s_psqt[bk]     : s_psqt[8 + bk];
            const float psqt   = (p_stm - p_opp) * 0.5f;
            out[b] = (psqt + scalar + skip) * (1.0f/16.0f);
        }
    }
}

extern "C" void kernel_launch(void* const* d_in, const int* in_sizes, int n_in,
                              void* d_out, int out_size, void* d_ws, size_t ws_size,
                              hipStream_t stream) {
    const int*   w_feats = (const int*)  d_in[0];
    // d_in[1] = w_offsets (uniform stride 32; unused, matching reference semantics)
    const int*   b_feats = (const int*)  d_in[2];
    // d_in[3] = b_offsets (unused)
    const int*   stm     = (const int*)  d_in[4];
    const int*   bucket  = (const int*)  d_in[5];
    const float* ft_w    = (const float*)d_in[6];
    const float* ft_bias = (const float*)d_in[7];
    const float* psqt_w  = (const float*)d_in[8];
    const float* fc0_w   = (const float*)d_in[9];
    const float* fc0_b   = (const float*)d_in[10];
    const float* fc1_w   = (const float*)d_in[11];
    const float* fc1_b   = (const float*)d_in[12];
    const float* fc2_w   = (const float*)d_in[13];
    const float* fc2_b   = (const float*)d_in[14];
    float* out = (float*)d_out;

    const int nB = in_sizes[4];  // number of samples (stm has one entry per sample)

    nnue_fwd<<<nB, 256, 0, stream>>>(w_feats, b_feats, stm, bucket,
                                     ft_w, ft_bias, psqt_w,
                                     fc0_w, fc0_b, fc1_w, fc1_b, fc2_w, fc2_b,
                                     out);
}

// Round 2
// 197.291 us; speedup vs baseline: 1.5357x; 1.5357x over previous
//
#include <hip/hip_runtime.h>
#include <hip/hip_fp16.h>

// NNUE (HalfKA) fused forward pass for MI355X.
// Round 2: ft_w converted to fp16 in d_ws each call (halves gather bytes);
// gather restructured to 16B fp16 loads; fp32 fallback if ws too small.

#define FEATS 32
#define FTO   1024
#define HH    512
#define FT_ELEMS (22528ULL * 1024ULL)   // fp16 bytes = 46,137,344

__device__ __forceinline__ float clip127(float x) {
    return fminf(fmaxf(x, 0.0f), 127.0f);
}

// ---------------- fp32 -> fp16 table conversion ----------------
__global__ __launch_bounds__(256) void cvt_f32_f16(const float* __restrict__ src,
                                                   uint2* __restrict__ dst,
                                                   unsigned n4) {
    unsigned i = blockIdx.x * blockDim.x + threadIdx.x;
    const unsigned stride = gridDim.x * blockDim.x;
    const float4* __restrict__ s4 = reinterpret_cast<const float4*>(src);
    for (; i < n4; i += stride) {
        const float4 v = s4[i];
        union { __half2 h[2]; uint2 u; } p;
        p.h[0] = __floats2half2_rn(v.x, v.y);
        p.h[1] = __floats2half2_rn(v.z, v.w);
        dst[i] = p.u;
    }
}

// ---------------- main fused kernel, fp16 table ----------------
__global__ __launch_bounds__(256) void nnue_fwd_h(
    const int*   __restrict__ w_feats,
    const int*   __restrict__ b_feats,
    const int*   __restrict__ stm,
    const int*   __restrict__ bucket,
    const uint4* __restrict__ ftw_h,     // fp16 table, 128 x uint4 per row
    const float* __restrict__ ft_bias,
    const float* __restrict__ psqt_w,
    const float* __restrict__ fc0_w,
    const float* __restrict__ fc0_b,
    const float* __restrict__ fc1_w,
    const float* __restrict__ fc1_b,
    const float* __restrict__ fc2_w,
    const float* __restrict__ fc2_b,
    float*       __restrict__ out)
{
    const int b   = blockIdx.x;
    const int tid = threadIdx.x;

    __shared__ int   sf[2 * FEATS];      // [0..31] w, [32..63] b
    __shared__ float s_acc[2][FTO];      // [0]=acc_stm, [1]=acc_opp
    __shared__ float s_part[4][16];
    __shared__ float s_o0[16];
    __shared__ float s_psqt[16];

    if (tid < FEATS)          sf[tid] = w_feats[b * FEATS + tid];
    else if (tid < 2 * FEATS) sf[tid] = b_feats[b * FEATS + (tid - FEATS)];
    __syncthreads();

    // ---- feature-transformer gather-sum over fp16 table ----
    // threads 0..127: w-bag; 128..255: b-bag. thread owns cols [8ct, 8ct+8).
    const bool isB = (tid >= 128);
    const int  ct  = tid & 127;
    const int* __restrict__ f = isB ? (sf + FEATS) : sf;

    float acc[8];
    {
        const float4 b0 = reinterpret_cast<const float4*>(ft_bias)[2 * ct];
        const float4 b1 = reinterpret_cast<const float4*>(ft_bias)[2 * ct + 1];
        acc[0] = b0.x; acc[1] = b0.y; acc[2] = b0.z; acc[3] = b0.w;
        acc[4] = b1.x; acc[5] = b1.y; acc[6] = b1.z; acc[7] = b1.w;
    }

    #pragma unroll 16
    for (int k = 0; k < FEATS; ++k) {
        const uint4 v = ftw_h[(size_t)f[k] * 128 + ct];
        const __half2* hp = reinterpret_cast<const __half2*>(&v);
        const float2 f0 = __half22float2(hp[0]);
        const float2 f1 = __half22float2(hp[1]);
        const float2 f2 = __half22float2(hp[2]);
        const float2 f3 = __half22float2(hp[3]);
        acc[0] += f0.x; acc[1] += f0.y; acc[2] += f1.x; acc[3] += f1.y;
        acc[4] += f2.x; acc[5] += f2.y; acc[6] += f3.x; acc[7] += f3.y;
    }

    // ---- psqt gather-sum (tiny table) ----
    if (tid < 16) {
        const int* ff = (tid < 8) ? sf : (sf + FEATS);
        const int  j  = tid & 7;
        float s = 0.0f;
        #pragma unroll 4
        for (int k = 0; k < FEATS; ++k) s += psqt_w[(size_t)ff[k] * 8 + j];
        s_psqt[tid] = s;
    }

    // acc_stm = stm ? acc_b : acc_w  -> w-threads write s_acc[st], b-threads s_acc[1-st]
    const int st  = stm[b];
    const int dst = isB ? (1 - st) : st;
    {
        float4* d = reinterpret_cast<float4*>(&s_acc[dst][8 * ct]);
        d[0] = make_float4(acc[0], acc[1], acc[2], acc[3]);
        d[1] = make_float4(acc[4], acc[5], acc[6], acc[7]);
    }
    __syncthreads();

    // ---- pairwise clip-mult ----
    float4 ft4;
    if (tid < 128) {
        const int h = 4 * tid;                 // [0, 512)
        const float4 lo = *reinterpret_cast<const float4*>(&s_acc[0][h]);
        const float4 hi = *reinterpret_cast<const float4*>(&s_acc[0][h + HH]);
        ft4.x = clip127(lo.x) * clip127(hi.x) * (1.0f/128.0f);
        ft4.y = clip127(lo.y) * clip127(hi.y) * (1.0f/128.0f);
        ft4.z = clip127(lo.z) * clip127(hi.z) * (1.0f/128.0f);
        ft4.w = clip127(lo.w) * clip127(hi.w) * (1.0f/128.0f);
    } else {
        const int j = 4 * (tid - 128);         // [0, 512)
        const float4 lo = *reinterpret_cast<const float4*>(&s_acc[1][j]);
        const float4 hi = *reinterpret_cast<const float4*>(&s_acc[1][j + HH]);
        ft4.x = clip127(lo.x) * clip127(hi.x) * (1.0f/128.0f);
        ft4.y = clip127(lo.y) * clip127(hi.y) * (1.0f/128.0f);
        ft4.z = clip127(lo.z) * clip127(hi.z) * (1.0f/128.0f);
        ft4.w = clip127(lo.w) * clip127(hi.w) * (1.0f/128.0f);
    }

    // ---- fc0: 16 outputs, dot over 1024 ----
    const int bk = bucket[b];
    const float4* __restrict__ w0 =
        reinterpret_cast<const float4*>(fc0_w + (size_t)bk * 16 * FTO);
    float p[16];
    #pragma unroll
    for (int o = 0; o < 16; ++o) {
        const float4 w = w0[o * 256 + tid];
        p[o] = ft4.x * w.x + ft4.y * w.y + ft4.z * w.z + ft4.w * w.w;
    }
    const int lane = tid & 63;
    const int wv   = tid >> 6;
    #pragma unroll
    for (int o = 0; o < 16; ++o) {
        float v = p[o];
        v += __shfl_down(v, 32);
        v += __shfl_down(v, 16);
        v += __shfl_down(v, 8);
        v += __shfl_down(v, 4);
        v += __shfl_down(v, 2);
        v += __shfl_down(v, 1);
        if (lane == 0) s_part[wv][o] = v;
    }
    __syncthreads();
    if (tid < 16) {
        s_o0[tid] = s_part[0][tid] + s_part[1][tid] + s_part[2][tid] + s_part[3][tid]
                  + fc0_b[bk * 16 + tid];
    }
    __syncthreads();

    // ---- tail: fc1 (32x32), fc2 (1x32), skip, psqt ----
    if (tid < 32) {
        const float* __restrict__ w1 = fc1_w + ((size_t)bk * 32 + tid) * 32;
        float o1 = fc1_b[bk * 32 + tid];
        #pragma unroll
        for (int i = 0; i < 15; ++i) {
            const float o0i = s_o0[i];
            const float sq  = clip127(o0i * o0i * (1.0f/524288.0f));
            const float rl  = clip127(o0i * (1.0f/64.0f));
            o1 += sq * w1[i] + rl * w1[15 + i];
        }
        const float ac1 = clip127(o1 * (1.0f/64.0f));
        float v = ac1 * fc2_w[bk * 32 + tid];
        v += __shfl_down(v, 16);
        v += __shfl_down(v, 8);
        v += __shfl_down(v, 4);
        v += __shfl_down(v, 2);
        v += __shfl_down(v, 1);
        if (tid == 0) {
            const float scalar = v + fc2_b[bk];
            const float skip   = s_o0[15] * (9600.0f / 8128.0f);
            const float p_stm  = st ? s_psqt[8 + bk] : s_psqt[bk];
            const float p_opp  = st ? s_psqt[bk]     : s_psqt[8 + bk];
            const float psqt   = (p_stm - p_opp) * 0.5f;
            out[b] = (psqt + scalar + skip) * (1.0f/16.0f);
        }
    }
}

// ---------------- fp32 fallback (round-1 kernel) ----------------
__global__ __launch_bounds__(256) void nnue_fwd_f32(
    const int*   __restrict__ w_feats,
    const int*   __restrict__ b_feats,
    const int*   __restrict__ stm,
    const int*   __restrict__ bucket,
    const float* __restrict__ ft_w,
    const float* __restrict__ ft_bias,
    const float* __restrict__ psqt_w,
    const float* __restrict__ fc0_w,
    const float* __restrict__ fc0_b,
    const float* __restrict__ fc1_w,
    const float* __restrict__ fc1_b,
    const float* __restrict__ fc2_w,
    const float* __restrict__ fc2_b,
    float*       __restrict__ out)
{
    const int b   = blockIdx.x;
    const int tid = threadIdx.x;

    __shared__ int   sfw[FEATS];
    __shared__ int   sfb[FEATS];
    __shared__ float s_acc[2][FTO];
    __shared__ float s_part[4][16];
    __shared__ float s_o0[16];
    __shared__ float s_psqt[16];

    if (tid < FEATS)          sfw[tid]         = w_feats[b * FEATS + tid];
    else if (tid < 2 * FEATS) sfb[tid - FEATS] = b_feats[b * FEATS + (tid - FEATS)];
    __syncthreads();

    const float4* __restrict__ ftw4 = reinterpret_cast<const float4*>(ft_w);
    const float4 bias4 = reinterpret_cast<const float4*>(ft_bias)[tid];
    float4 aw = bias4, ab = bias4;

    #pragma unroll 8
    for (int k = 0; k < FEATS; ++k) {
        const float4 rw = ftw4[(size_t)sfw[k] * 256 + tid];
        const float4 rb = ftw4[(size_t)sfb[k] * 256 + tid];
        aw.x += rw.x; aw.y += rw.y; aw.z += rw.z; aw.w += rw.w;
        ab.x += rb.x; ab.y += rb.y; ab.z += rb.z; ab.w += rb.w;
    }

    if (tid < 16) {
        const int* f = (tid < 8) ? sfw : sfb;
        const int  j = tid & 7;
        float s = 0.0f;
        #pragma unroll 4
        for (int k = 0; k < FEATS; ++k) s += psqt_w[(size_t)f[k] * 8 + j];
        s_psqt[tid] = s;
    }

    const int st = stm[b];
    const float4 astm = st ? ab : aw;
    const float4 aopp = st ? aw : ab;

    reinterpret_cast<float4*>(&s_acc[0][0])[tid] = astm;
    reinterpret_cast<float4*>(&s_acc[1][0])[tid] = aopp;
    __syncthreads();

    float4 ft4;
    if (tid < 128) {
        const float4 lo = astm;
        const float4 hi = *reinterpret_cast<const float4*>(&s_acc[0][HH + tid * 4]);
        ft4.x = clip127(lo.x) * clip127(hi.x) * (1.0f/128.0f);
        ft4.y = clip127(lo.y) * clip127(hi.y) * (1.0f/128.0f);
        ft4.z = clip127(lo.z) * clip127(hi.z) * (1.0f/128.0f);
        ft4.w = clip127(lo.w) * clip127(hi.w) * (1.0f/128.0f);
    } else {
        const float4 lo = *reinterpret_cast<const float4*>(&s_acc[1][(tid - 128) * 4]);
        const float4 hi = aopp;
        ft4.x = clip127(lo.x) * clip127(hi.x) * (1.0f/128.0f);
        ft4.y = clip127(lo.y) * clip127(hi.y) * (1.0f/128.0f);
        ft4.z = clip127(lo.z) * clip127(hi.z) * (1.0f/128.0f);
        ft4.w = clip127(lo.w) * clip127(hi.w) * (1.0f/128.0f);
    }

    const int bk = bucket[b];
    const float4* __restrict__ w0 =
        reinterpret_cast<const float4*>(fc0_w + (size_t)bk * 16 * FTO);
    float p[16];
    #pragma unroll
    for (int o = 0; o < 16; ++o) {
        const float4 w = w0[o * 256 + tid];
        p[o] = ft4.x * w.x + ft4.y * w.y + ft4.z * w.z + ft4.w * w.w;
    }
    const int lane = tid & 63;
    const int wv   = tid >> 6;
    #pragma unroll
    for (int o = 0; o < 16; ++o) {
        float v = p[o];
        v += __shfl_down(v, 32);
        v += __shfl_down(v, 16);
        v += __shfl_down(v, 8);
        v += __shfl_down(v, 4);
        v += __shfl_down(v, 2);
        v += __shfl_down(v, 1);
        if (lane == 0) s_part[wv][o] = v;
    }
    __syncthreads();
    if (tid < 16) {
        s_o0[tid] = s_part[0][tid] + s_part[1][tid] + s_part[2][tid] + s_part[3][tid]
                  + fc0_b[bk * 16 + tid];
    }
    __syncthreads();

    if (tid < 32) {
        const float* __restrict__ w1 = fc1_w + ((size_t)bk * 32 + tid) * 32;
        float o1 = fc1_b[bk * 32 + tid];
        #pragma unroll
        for (int i = 0; i < 15; ++i) {
            const float o0i = s_o0[i];
            const float sq  = clip127(o0i * o0i * (1.0f/524288.0f));
            const float rl  = clip127(o0i * (1.0f/64.0f));
            o1 += sq * w1[i] + rl * w1[15 + i];
        }
        const float ac1 = clip127(o1 * (1.0f/64.0f));
        float v = ac1 * fc2_w[bk * 32 + tid];
        v += __shfl_down(v, 16);
        v += __shfl_down(v, 8);
        v += __shfl_down(v, 4);
        v += __shfl_down(v, 2);
        v += __shfl_down(v, 1);
        if (tid == 0) {
            const float scalar = v + fc2_b[bk];
            const float skip   = s_o0[15] * (9600.0f / 8128.0f);
            const float p_stm  = st ? s_psqt[8 + bk] : s_psqt[bk];
            const float p_opp  = st ? s_psqt[bk]     : s_psqt[8 + bk];
            const float psqt   = (p_stm - p_opp) * 0.5f;
            out[b] = (psqt + scalar + skip) * (1.0f/16.0f);
        }
    }
}

extern "C" void kernel_launch(void* const* d_in, const int* in_sizes, int n_in,
                              void* d_out, int out_size, void* d_ws, size_t ws_size,
                              hipStream_t stream) {
    const int*   w_feats = (const int*)  d_in[0];
    const int*   b_feats = (const int*)  d_in[2];
    const int*   stm     = (const int*)  d_in[4];
    const int*   bucket  = (const int*)  d_in[5];
    const float* ft_w    = (const float*)d_in[6];
    const float* ft_bias = (const float*)d_in[7];
    const float* psqt_w  = (const float*)d_in[8];
    const float* fc0_w   = (const float*)d_in[9];
    const float* fc0_b   = (const float*)d_in[10];
    const float* fc1_w   = (const float*)d_in[11];
    const float* fc1_b   = (const float*)d_in[12];
    const float* fc2_w   = (const float*)d_in[13];
    const float* fc2_b   = (const float*)d_in[14];
    float* out = (float*)d_out;

    const int nB = in_sizes[4];

    const size_t need = FT_ELEMS * sizeof(__half);   // 46,137,344 B
    if (ws_size >= need) {
        const unsigned n4 = (unsigned)(FT_ELEMS / 4);
        cvt_f32_f16<<<2048, 256, 0, stream>>>(ft_w, (uint2*)d_ws, n4);
        nnue_fwd_h<<<nB, 256, 0, stream>>>(w_feats, b_feats, stm, bucket,
                                           (const uint4*)d_ws, ft_bias, psqt_w,
                                           fc0_w, fc0_b, fc1_w, fc1_b, fc2_w, fc2_b,
                                           out);
    } else {
        nnue_fwd_f32<<<nB, 256, 0, stream>>>(w_feats, b_feats, stm, bucket,
                                             ft_w, ft_bias, psqt_w,
                                             fc0_w, fc0_b, fc1_w, fc1_b, fc2_w, fc2_b,
                                             out);
    }
}

// Round 3
// 128.306 us; speedup vs baseline: 2.3614x; 1.5377x over previous
//
#include <hip/hip_runtime.h>
#include <hip/hip_fp16.h>

// NNUE (HalfKA) fused forward pass for MI355X.
// Round 3: ft_w quantized to biased-int8 in d_ws (quarter of fp32 bytes);
// gather accumulates packed u16 pairs via v_perm zero-extension; decode
// (scale+bias) deferred to the pairwise step. fp32 fallback if ws too small.

#define FEATS 32
#define FTO   1024
#define HH    512
#define FT_ELEMS (22528ULL * 1024ULL)      // int8 bytes = 23,068,672
#define QSCALE   (6.0f / 127.0f)

__device__ __forceinline__ float clip127(float x) {
    return fminf(fmaxf(x, 0.0f), 127.0f);
}

// ---------------- fp32 -> biased int8 quantize ----------------
__global__ __launch_bounds__(256) void quant_f32_u8(const float4* __restrict__ src,
                                                    uint4* __restrict__ dst,
                                                    unsigned n16) {
    unsigned i = blockIdx.x * 256 + threadIdx.x;
    const unsigned stride = gridDim.x * 256;
    const float inv = 127.0f / 6.0f;
    for (; i < n16; i += stride) {
        unsigned w[4];
        #pragma unroll
        for (int j = 0; j < 4; ++j) {
            const float4 v = src[4 * (size_t)i + j];
            const unsigned q0 = (unsigned)(__float2int_rn(fminf(fmaxf(v.x * inv, -127.f), 127.f)) + 128);
            const unsigned q1 = (unsigned)(__float2int_rn(fminf(fmaxf(v.y * inv, -127.f), 127.f)) + 128);
            const unsigned q2 = (unsigned)(__float2int_rn(fminf(fmaxf(v.z * inv, -127.f), 127.f)) + 128);
            const unsigned q3 = (unsigned)(__float2int_rn(fminf(fmaxf(v.w * inv, -127.f), 127.f)) + 128);
            w[j] = q0 | (q1 << 8) | (q2 << 16) | (q3 << 24);
        }
        dst[i] = make_uint4(w[0], w[1], w[2], w[3]);
    }
}

// ---------------- main fused kernel, int8 table ----------------
// Wave roles: wave = tid>>6; bag = wave>>1 (0=w,1=b); half = wave&1.
// Each wave gathers 16 full rows (64 lanes x 16B = 1024B = one int8 row).
// Lane owns cols [16*lane, 16*lane+16), accumulated as 8 packed-u16 words.
__global__ __launch_bounds__(256) void nnue_fwd_q8(
    const int*   __restrict__ w_feats,
    const int*   __restrict__ b_feats,
    const int*   __restrict__ stm,
    const int*   __restrict__ bucket,
    const uint4* __restrict__ tbl,       // int8 table, 64 x uint4 per row
    const float* __restrict__ ft_bias,
    const float* __restrict__ psqt_w,
    const float* __restrict__ fc0_w,
    const float* __restrict__ fc0_b,
    const float* __restrict__ fc1_w,
    const float* __restrict__ fc1_b,
    const float* __restrict__ fc2_w,
    const float* __restrict__ fc2_b,
    float*       __restrict__ out)
{
    const int b    = blockIdx.x;
    const int tid  = threadIdx.x;
    const int lane = tid & 63;
    const int wv   = tid >> 6;
    const int bag  = wv >> 1;
    const int half = wv & 1;

    __shared__ int      sf[2 * FEATS];          // [0..31] w, [32..63] b
    __shared__ unsigned pk[2][2][512];          // [dst][half][word] packed u16 pairs
    __shared__ float    s_part[4][16];
    __shared__ float    s_o0[16];
    __shared__ float    s_psqt[16];

    if (tid < FEATS)          sf[tid] = w_feats[b * FEATS + tid];
    else if (tid < 2 * FEATS) sf[tid] = b_feats[b * FEATS + (tid - FEATS)];
    __syncthreads();

    // ---- gather-sum 16 rows as packed u16 pairs ----
    const int* __restrict__ f = sf + bag * FEATS + half * 16;
    unsigned pa[8] = {0, 0, 0, 0, 0, 0, 0, 0};

    #pragma unroll
    for (int k = 0; k < 16; ++k) {
        const uint4 v = tbl[(size_t)f[k] * 64 + lane];
        pa[0] += __builtin_amdgcn_perm(v.x, v.x, 0x0C010C00u);
        pa[1] += __builtin_amdgcn_perm(v.x, v.x, 0x0C030C02u);
        pa[2] += __builtin_amdgcn_perm(v.y, v.y, 0x0C010C00u);
        pa[3] += __builtin_amdgcn_perm(v.y, v.y, 0x0C030C02u);
        pa[4] += __builtin_amdgcn_perm(v.z, v.z, 0x0C010C00u);
        pa[5] += __builtin_amdgcn_perm(v.z, v.z, 0x0C030C02u);
        pa[6] += __builtin_amdgcn_perm(v.w, v.w, 0x0C010C00u);
        pa[7] += __builtin_amdgcn_perm(v.w, v.w, 0x0C030C02u);
    }

    const int st  = stm[b];
    const int dst = bag ? (1 - st) : st;
    {
        unsigned* pw = &pk[dst][half][lane * 8];
        reinterpret_cast<uint4*>(pw)[0] = make_uint4(pa[0], pa[1], pa[2], pa[3]);
        reinterpret_cast<uint4*>(pw)[1] = make_uint4(pa[4], pa[5], pa[6], pa[7]);
    }

    // ---- psqt gather-sum (tiny fp32 table) ----
    if (tid < 16) {
        const int* ff = (tid < 8) ? sf : (sf + FEATS);
        const int  j  = tid & 7;
        float s = 0.0f;
        #pragma unroll 4
        for (int k = 0; k < FEATS; ++k) s += psqt_w[(size_t)ff[k] * 8 + j];
        s_psqt[tid] = s;
    }
    __syncthreads();

    // ---- combine halves, decode, pairwise clip-mult ----
    // thread t handles global ft cols [4t, 4t+4):
    //   t<128  -> dst 0 (acc_stm), cols cb=4t      : a0[cb..]*a0[cb+512..]
    //   t>=128 -> dst 1 (acc_opp), cols cb=4(t-128): a1[cb..]*a1[cb+512..]
    const int d   = (tid < 128) ? 0 : 1;
    const int tau = tid & 127;

    const uint2 l0 = *reinterpret_cast<const uint2*>(&pk[d][0][2 * tau]);
    const uint2 l1 = *reinterpret_cast<const uint2*>(&pk[d][1][2 * tau]);
    const uint2 h0 = *reinterpret_cast<const uint2*>(&pk[d][0][2 * tau + 256]);
    const uint2 h1 = *reinterpret_cast<const uint2*>(&pk[d][1][2 * tau + 256]);
    const unsigned wl0 = l0.x + l1.x, wl1 = l0.y + l1.y;   // u16 lanes: cols cb..cb+3
    const unsigned wh0 = h0.x + h1.x, wh1 = h0.y + h1.y;   // cols cb+512..cb+515

    const float4 fb_lo = reinterpret_cast<const float4*>(ft_bias)[tau];
    const float4 fb_hi = reinterpret_cast<const float4*>(ft_bias)[tau + 128];
    const float  qs    = QSCALE;
    const float  qoff  = -4096.0f * QSCALE;   // 32 rows * 128 bias

    float4 alo, ahi;
    alo.x = (float)(wl0 & 0xFFFFu) * qs + (fb_lo.x + qoff);
    alo.y = (float)(wl0 >> 16)     * qs + (fb_lo.y + qoff);
    alo.z = (float)(wl1 & 0xFFFFu) * qs + (fb_lo.z + qoff);
    alo.w = (float)(wl1 >> 16)     * qs + (fb_lo.w + qoff);
    ahi.x = (float)(wh0 & 0xFFFFu) * qs + (fb_hi.x + qoff);
    ahi.y = (float)(wh0 >> 16)     * qs + (fb_hi.y + qoff);
    ahi.z = (float)(wh1 & 0xFFFFu) * qs + (fb_hi.z + qoff);
    ahi.w = (float)(wh1 >> 16)     * qs + (fb_hi.w + qoff);

    float4 ft4;
    ft4.x = clip127(alo.x) * clip127(ahi.x) * (1.0f/128.0f);
    ft4.y = clip127(alo.y) * clip127(ahi.y) * (1.0f/128.0f);
    ft4.z = clip127(alo.z) * clip127(ahi.z) * (1.0f/128.0f);
    ft4.w = clip127(alo.w) * clip127(ahi.w) * (1.0f/128.0f);

    // ---- fc0: 16 outputs, dot over 1024 ----
    const int bk = bucket[b];
    const float4* __restrict__ w0 =
        reinterpret_cast<const float4*>(fc0_w + (size_t)bk * 16 * FTO);
    float p[16];
    #pragma unroll
    for (int o = 0; o < 16; ++o) {
        const float4 w = w0[o * 256 + tid];
        p[o] = ft4.x * w.x + ft4.y * w.y + ft4.z * w.z + ft4.w * w.w;
    }
    #pragma unroll
    for (int o = 0; o < 16; ++o) {
        float v = p[o];
        v += __shfl_down(v, 32);
        v += __shfl_down(v, 16);
        v += __shfl_down(v, 8);
        v += __shfl_down(v, 4);
        v += __shfl_down(v, 2);
        v += __shfl_down(v, 1);
        if (lane == 0) s_part[wv][o] = v;
    }
    __syncthreads();
    if (tid < 16) {
        s_o0[tid] = s_part[0][tid] + s_part[1][tid] + s_part[2][tid] + s_part[3][tid]
                  + fc0_b[bk * 16 + tid];
    }
    __syncthreads();

    // ---- tail: fc1 (32x32), fc2 (1x32), skip, psqt ----
    if (tid < 32) {
        const float* __restrict__ w1 = fc1_w + ((size_t)bk * 32 + tid) * 32;
        float o1 = fc1_b[bk * 32 + tid];
        #pragma unroll
        for (int i = 0; i < 15; ++i) {
            const float o0i = s_o0[i];
            const float sq  = clip127(o0i * o0i * (1.0f/524288.0f));
            const float rl  = clip127(o0i * (1.0f/64.0f));
            o1 += sq * w1[i] + rl * w1[15 + i];
        }
        const float ac1 = clip127(o1 * (1.0f/64.0f));
        float v = ac1 * fc2_w[bk * 32 + tid];
        v += __shfl_down(v, 16);
        v += __shfl_down(v, 8);
        v += __shfl_down(v, 4);
        v += __shfl_down(v, 2);
        v += __shfl_down(v, 1);
        if (tid == 0) {
            const float scalar = v + fc2_b[bk];
            const float skip   = s_o0[15] * (9600.0f / 8128.0f);
            const float p_stm  = st ? s_psqt[8 + bk] : s_psqt[bk];
            const float p_opp  = st ? s_psqt[bk]     : s_psqt[8 + bk];
            const float psqt   = (p_stm - p_opp) * 0.5f;
            out[b] = (psqt + scalar + skip) * (1.0f/16.0f);
        }
    }
}

// ---------------- fp32 fallback (round-1 kernel) ----------------
__global__ __launch_bounds__(256) void nnue_fwd_f32(
    const int*   __restrict__ w_feats,
    const int*   __restrict__ b_feats,
    const int*   __restrict__ stm,
    const int*   __restrict__ bucket,
    const float* __restrict__ ft_w,
    const float* __restrict__ ft_bias,
    const float* __restrict__ psqt_w,
    const float* __restrict__ fc0_w,
    const float* __restrict__ fc0_b,
    const float* __restrict__ fc1_w,
    const float* __restrict__ fc1_b,
    const float* __restrict__ fc2_w,
    const float* __restrict__ fc2_b,
    float*       __restrict__ out)
{
    const int b   = blockIdx.x;
    const int tid = threadIdx.x;

    __shared__ int   sfw[FEATS];
    __shared__ int   sfb[FEATS];
    __shared__ float s_acc[2][FTO];
    __shared__ float s_part[4][16];
    __shared__ float s_o0[16];
    __shared__ float s_psqt[16];

    if (tid < FEATS)          sfw[tid]         = w_feats[b * FEATS + tid];
    else if (tid < 2 * FEATS) sfb[tid - FEATS] = b_feats[b * FEATS + (tid - FEATS)];
    __syncthreads();

    const float4* __restrict__ ftw4 = reinterpret_cast<const float4*>(ft_w);
    const float4 bias4 = reinterpret_cast<const float4*>(ft_bias)[tid];
    float4 aw = bias4, ab = bias4;

    #pragma unroll 8
    for (int k = 0; k < FEATS; ++k) {
        const float4 rw = ftw4[(size_t)sfw[k] * 256 + tid];
        const float4 rb = ftw4[(size_t)sfb[k] * 256 + tid];
        aw.x += rw.x; aw.y += rw.y; aw.z += rw.z; aw.w += rw.w;
        ab.x += rb.x; ab.y += rb.y; ab.z += rb.z; ab.w += rb.w;
    }

    if (tid < 16) {
        const int* f = (tid < 8) ? sfw : sfb;
        const int  j = tid & 7;
        float s = 0.0f;
        #pragma unroll 4
        for (int k = 0; k < FEATS; ++k) s += psqt_w[(size_t)f[k] * 8 + j];
        s_psqt[tid] = s;
    }

    const int st = stm[b];
    const float4 astm = st ? ab : aw;
    const float4 aopp = st ? aw : ab;

    reinterpret_cast<float4*>(&s_acc[0][0])[tid] = astm;
    reinterpret_cast<float4*>(&s_acc[1][0])[tid] = aopp;
    __syncthreads();

    float4 ft4;
    if (tid < 128) {
        const float4 lo = astm;
        const float4 hi = *reinterpret_cast<const float4*>(&s_acc[0][HH + tid * 4]);
        ft4.x = clip127(lo.x) * clip127(hi.x) * (1.0f/128.0f);
        ft4.y = clip127(lo.y) * clip127(hi.y) * (1.0f/128.0f);
        ft4.z = clip127(lo.z) * clip127(hi.z) * (1.0f/128.0f);
        ft4.w = clip127(lo.w) * clip127(hi.w) * (1.0f/128.0f);
    } else {
        const float4 lo = *reinterpret_cast<const float4*>(&s_acc[1][(tid - 128) * 4]);
        const float4 hi = aopp;
        ft4.x = clip127(lo.x) * clip127(hi.x) * (1.0f/128.0f);
        ft4.y = clip127(lo.y) * clip127(hi.y) * (1.0f/128.0f);
        ft4.z = clip127(lo.z) * clip127(hi.z) * (1.0f/128.0f);
        ft4.w = clip127(lo.w) * clip127(hi.w) * (1.0f/128.0f);
    }

    const int bk = bucket[b];
    const float4* __restrict__ w0 =
        reinterpret_cast<const float4*>(fc0_w + (size_t)bk * 16 * FTO);
    float p[16];
    #pragma unroll
    for (int o = 0; o < 16; ++o) {
        const float4 w = w0[o * 256 + tid];
        p[o] = ft4.x * w.x + ft4.y * w.y + ft4.z * w.z + ft4.w * w.w;
    }
    const int lane = tid & 63;
    const int wv   = tid >> 6;
    #pragma unroll
    for (int o = 0; o < 16; ++o) {
        float v = p[o];
        v += __shfl_down(v, 32);
        v += __shfl_down(v, 16);
        v += __shfl_down(v, 8);
        v += __shfl_down(v, 4);
        v += __shfl_down(v, 2);
        v += __shfl_down(v, 1);
        if (lane == 0) s_part[wv][o] = v;
    }
    __syncthreads();
    if (tid < 16) {
        s_o0[tid] = s_part[0][tid] + s_part[1][tid] + s_part[2][tid] + s_part[3][tid]
                  + fc0_b[bk * 16 + tid];
    }
    __syncthreads();

    if (tid < 32) {
        const float* __restrict__ w1 = fc1_w + ((size_t)bk * 32 + tid) * 32;
        float o1 = fc1_b[bk * 32 + tid];
        #pragma unroll
        for (int i = 0; i < 15; ++i) {
            const float o0i = s_o0[i];
            const float sq  = clip127(o0i * o0i * (1.0f/524288.0f));
            const float rl  = clip127(o0i * (1.0f/64.0f));
            o1 += sq * w1[i] + rl * w1[15 + i];
        }
        const float ac1 = clip127(o1 * (1.0f/64.0f));
        float v = ac1 * fc2_w[bk * 32 + tid];
        v += __shfl_down(v, 16);
        v += __shfl_down(v, 8);
        v += __shfl_down(v, 4);
        v += __shfl_down(v, 2);
        v += __shfl_down(v, 1);
        if (tid == 0) {
            const float scalar = v + fc2_b[bk];
            const float skip   = s_o0[15] * (9600.0f / 8128.0f);
            const float p_stm  = st ? s_psqt[8 + bk] : s_psqt[bk];
            const float p_opp  = st ? s_psqt[bk]     : s_psqt[8 + bk];
            const float psqt   = (p_stm - p_opp) * 0.5f;
            out[b] = (psqt + scalar + skip) * (1.0f/16.0f);
        }
    }
}

extern "C" void kernel_launch(void* const* d_in, const int* in_sizes, int n_in,
                              void* d_out, int out_size, void* d_ws, size_t ws_size,
                              hipStream_t stream) {
    const int*   w_feats = (const int*)  d_in[0];
    const int*   b_feats = (const int*)  d_in[2];
    const int*   stm     = (const int*)  d_in[4];
    const int*   bucket  = (const int*)  d_in[5];
    const float* ft_w    = (const float*)d_in[6];
    const float* ft_bias = (const float*)d_in[7];
    const float* psqt_w  = (const float*)d_in[8];
    const float* fc0_w   = (const float*)d_in[9];
    const float* fc0_b   = (const float*)d_in[10];
    const float* fc1_w   = (const float*)d_in[11];
    const float* fc1_b   = (const float*)d_in[12];
    const float* fc2_w   = (const float*)d_in[13];
    const float* fc2_b   = (const float*)d_in[14];
    float* out = (float*)d_out;

    const int nB = in_sizes[4];

    const size_t need = FT_ELEMS;   // 23,068,672 B of int8
    if (ws_size >= need) {
        const unsigned n16 = (unsigned)(FT_ELEMS / 16);
        quant_f32_u8<<<2048, 256, 0, stream>>>((const float4*)ft_w, (uint4*)d_ws, n16);
        nnue_fwd_q8<<<nB, 256, 0, stream>>>(w_feats, b_feats, stm, bucket,
                                            (const uint4*)d_ws, ft_bias, psqt_w,
                                            fc0_w, fc0_b, fc1_w, fc1_b, fc2_w, fc2_b,
                                            out);
    } else {
        nnue_fwd_f32<<<nB, 256, 0, stream>>>(w_feats, b_feats, stm, bucket,
                                             ft_w, ft_bias, psqt_w,
                                             fc0_w, fc0_b, fc1_w, fc1_b, fc2_w, fc2_b,
                                             out);
    }
}